// Round 10
// baseline (335.584 us; speedup 1.0000x reference)
//
#include <hip/hip_runtime.h>
#include <math.h>

#define BATCH 512
#define DIM   1024
#define NCLUS 16384
#define TINV  20.0f   // 1/TEMP

typedef __attribute__((ext_vector_type(4))) float f32x4;
typedef __attribute__((ext_vector_type(2))) float f32x2;
typedef __attribute__((ext_vector_type(8))) short bf16x8;

static __device__ __forceinline__ unsigned short f2bf(float f) {
  unsigned int u = __float_as_uint(f);
  u += 0x7FFFu + ((u >> 16) & 1u);   // round-to-nearest-even
  return (unsigned short)(u >> 16);
}

typedef const __attribute__((address_space(1))) unsigned int* gas1_t;
typedef __attribute__((address_space(3))) unsigned int* las3_t;
// async global->LDS, 16B per lane; LDS dest = wave-uniform base + lane*16
static __device__ __forceinline__ void gload16(const void* g, void* l) {
  __builtin_amdgcn_global_load_lds((gas1_t)g, (las3_t)l, 16, 0, 0);
}

// ---------------------------------------------------------------------------
// Kernel 1: row L2-normalize (both modalities), emit f32 + bf16 copies of x.
// Also zeroes the 2048-float accumulator region (rowsum + tgtlog).
// ---------------------------------------------------------------------------
__global__ void nrm_kernel(const float* __restrict__ in_rgb,
                           const float* __restrict__ in_ir,
                           float* __restrict__ xf,            // [2][512][1024]
                           unsigned short* __restrict__ xb,   // [2][512][1024]
                           float* __restrict__ accum) {       // 2048 floats
  int gid = blockIdx.x * blockDim.x + threadIdx.x;
  if (gid < 2048) accum[gid] = 0.0f;

  int row = blockIdx.x;
  int mod = row >> 9;
  int r   = row & 511;
  const float* in = (mod ? in_ir : in_rgb) + (size_t)r * DIM;
  float* xo          = xf + ((size_t)mod * BATCH + r) * DIM;
  unsigned short* xbo = xb + ((size_t)mod * BATCH + r) * DIM;

  int t = threadIdx.x;
  float4 v = ((const float4*)in)[t];
  float ss = v.x*v.x + v.y*v.y + v.z*v.z + v.w*v.w;
#pragma unroll
  for (int m = 1; m < 64; m <<= 1) ss += __shfl_xor(ss, m, 64);
  __shared__ float red[4];
  if ((t & 63) == 0) red[t >> 6] = ss;
  __syncthreads();
  float inv = 1.0f / fmaxf(sqrtf(red[0] + red[1] + red[2] + red[3]), 1e-12f);
  float4 o = make_float4(v.x * inv, v.y * inv, v.z * inv, v.w * inv);
  ((float4*)xo)[t] = o;
  ushort4 ob = make_ushort4(f2bf(o.x), f2bf(o.y), f2bf(o.z), f2bf(o.w));
  ((ushort4*)xbo)[t] = ob;
}

// ---------------------------------------------------------------------------
// Kernel 2: HETEROGENEOUS fused dispatch — 2048 blocks x 256 threads.
//   role = (blockIdx.x>>3)&1:  0 -> GEMM block (1024), 1 -> copy block (1024)
// Roles alternate per XCD (idx%8 = XCD round-robin), so every CU hosts
// ~3 gemm blocks (latency-bound, HBM-idle) + copy blocks (pure HBM) —
// the copy rides the GEMM's idle memory pipe (m114 co-schedule).
//
// GEMM: 128x128 tile, BK=32, 4 waves (2x2) each 64x64, proven 2-buf loop.
//  - A (x, bf16): global_load_lds + XOR-swizzle (this round's verified
//    conflict-free pair: source chunk cs=(q&3)^((q>>3)&3), read ^(l15&6)<<3).
//  - B (F, f32): loaded per-wave global->reg, truncate-packed to bf16 in
//    register (2 ops/pair; ~1e-2 logit error vs 0.1975 threshold).
//    fb/cvtcopy eliminated entirely -> no GEMM<-copy dependency.
//  - Gate order: A-gloads issued FIRST, B-reg loads after; vmcnt(8) retires
//    only the 2 A ops, B's 8 stay in flight across the barrier (T4).
//    lgkmcnt(0)+sched_barrier(0) before s_barrier (rule #18).
// nt = xcd + 8*q -> the 4 bt-blocks of each (nt,mod) panel share one XCD.
// ---------------------------------------------------------------------------
#define BM 128
#define BK 32
#define NSTEP (DIM / BK)   // 32

__launch_bounds__(256, 2)
__global__ void fused_kernel(const unsigned short* __restrict__ xb,
                             const float* __restrict__ f_rgb,
                             const float* __restrict__ f_ir,
                             const int* __restrict__ t_rgb,
                             const int* __restrict__ t_ir,
                             float* __restrict__ outc,     // d_out + 2
                             float* __restrict__ rowsum,   // [2][512]
                             float* __restrict__ tgtlog) { // [2][512]
  const int xcd = blockIdx.x & 7;
  const int o   = blockIdx.x >> 3;
  const int tid = threadIdx.x;

  if (o & 1) {
    // ---------------- copy role: banks -> d_out, f32 exact ----------------
    const size_t n4 = (size_t)NCLUS * DIM / 4;
    const int cid = (o >> 1) * 8 + xcd;            // 0..1023
    for (size_t i = (size_t)cid * 256 + tid; i < 2 * n4; i += 1024 * 256) {
      const f32x4* src = (i < n4) ? ((const f32x4*)f_rgb) + i
                                  : ((const f32x4*)f_ir) + (i - n4);
      const f32x4 v = __builtin_nontemporal_load(src);
      f32x2* o2 = (f32x2*)(outc + 4 * i);
      __builtin_nontemporal_store((f32x2){v.x, v.y}, o2);
      __builtin_nontemporal_store((f32x2){v.z, v.w}, o2 + 1);
    }
    return;
  }

  // ------------------------------ GEMM role -------------------------------
  const int j   = o >> 1;          // 0..127
  const int nt  = xcd + 8 * (j >> 3);   // 0..127, XCD-grouped panels
  const int bt  = j & 3;
  const int mod = (j >> 2) & 1;

  const unsigned short* X = xb + ((size_t)mod * BATCH + bt * BM) * DIM;
  const float* Fbase = mod ? f_ir : f_rgb;
  const int* tg = mod ? t_ir : t_rgb;
  float* rs = rowsum + mod * BATCH;
  float* tl = tgtlog + mod * BATCH;

  __shared__ __align__(16) unsigned short As[2][BM * BK];  // 16 KB

  const int wid  = tid >> 6;
  const int lane = tid & 63;
  const int wr = wid >> 1, wc = wid & 1;
  const int l15 = lane & 15, lhi = lane >> 4;
  const int sw = (l15 & 6) << 3;       // read-side bank-spread XOR (bytes)

  // per-lane B base: frag n row = wc*64 + n*16 + l15, k-offset lhi*8
  const float* Fp = Fbase + ((size_t)nt * BM + wc * 64 + l15) * DIM + lhi * 8;

  f32x4 acc[4][4];
#pragma unroll
  for (int m = 0; m < 4; ++m)
#pragma unroll
    for (int n = 0; n < 4; ++n) acc[m][n] = (f32x4){0.f, 0.f, 0.f, 0.f};

  auto STAGE_A = [&](int buf, int kt) {   // 2 gload16 per thread
#pragma unroll
    for (int c = 0; c < 2; ++c) {
      int q = c * 256 + tid;                    // chunk 0..511
      int cs = (q & 3) ^ ((q >> 3) & 3);        // inverse swizzle (involution)
      gload16(X + (size_t)(q >> 2) * DIM + kt * BK + cs * 8,
              &As[buf][(c * 256 + wid * 64) * 8]);
    }
  };
  auto B_LOAD = [&](f32x4* raw, int kk) {  // 8 dwordx4 per lane
#pragma unroll
    for (int n = 0; n < 4; ++n) {
      raw[2 * n]     = *(const f32x4*)(Fp + (size_t)n * 16 * DIM + kk);
      raw[2 * n + 1] = *(const f32x4*)(Fp + (size_t)n * 16 * DIM + kk + 4);
    }
  };
  auto PACK = [&](const f32x4* raw, bf16x8* pk) {  // truncation (high 16 bits)
#pragma unroll
    for (int n = 0; n < 4; ++n) {
      union { bf16x8 v; unsigned int u[4]; } t;
      const unsigned int* a0 = (const unsigned int*)&raw[2 * n];
      const unsigned int* a1 = (const unsigned int*)&raw[2 * n + 1];
      t.u[0] = (a0[0] >> 16) | (a0[1] & 0xFFFF0000u);
      t.u[1] = (a0[2] >> 16) | (a0[3] & 0xFFFF0000u);
      t.u[2] = (a1[0] >> 16) | (a1[1] & 0xFFFF0000u);
      t.u[3] = (a1[2] >> 16) | (a1[3] & 0xFFFF0000u);
      pk[n] = t.v;
    }
  };
  auto LDA = [&](int buf, int row) {
    return *(const bf16x8*)((const char*)As[buf] + ((row * 64 + lhi * 16) ^ sw));
  };
  auto COMPUTE = [&](int buf, const bf16x8* pk) {
    bf16x8 a[4];
#pragma unroll
    for (int m = 0; m < 4; ++m) a[m] = LDA(buf, wr * 64 + m * 16 + l15);
#pragma unroll
    for (int m = 0; m < 4; ++m)
#pragma unroll
      for (int n = 0; n < 4; ++n)
        acc[m][n] = __builtin_amdgcn_mfma_f32_16x16x32_bf16(a[m], pk[n], acc[m][n], 0, 0, 0);
  };

  f32x4 raw[8];
  bf16x8 pk[4];
  B_LOAD(raw, 0);
  STAGE_A(0, 0);
  __syncthreads();                       // prologue full drain (once)

  for (int s = 0; s < NSTEP - 1; ++s) {
    PACK(raw, pk);                       // B(s) -> bf16 regs (frees raw)
    STAGE_A((s + 1) & 1, s + 1);         // A gloads FIRST (oldest in queue)
    B_LOAD(raw, (s + 1) * BK);           // B(s+1) after (newest 8)
    COMPUTE(s & 1, pk);
    // retire the 2 A gloads (oldest); keep B's 8 in flight across barrier
    asm volatile("s_waitcnt vmcnt(8) lgkmcnt(0)" ::: "memory");
    __builtin_amdgcn_sched_barrier(0);
    __builtin_amdgcn_s_barrier();
  }
  PACK(raw, pk);
  COMPUTE((NSTEP - 1) & 1, pk);

  // epilogue: exp-sum over this tile's 128 cols + target capture
#pragma unroll
  for (int m = 0; m < 4; ++m) {
    const int browbase = bt * BM + wr * 64 + m * 16 + lhi * 4;
    float esum[4];
#pragma unroll
    for (int j2 = 0; j2 < 4; ++j2) {
      const int brow = browbase + j2;
      const int t = tg[brow];
      float e = 0.f;
#pragma unroll
      for (int n = 0; n < 4; ++n) {
        float logit = acc[m][n][j2] * TINV;
        e += __expf(logit);
        int col = nt * BM + wc * 64 + n * 16 + l15;
        if (col == t) tl[brow] = logit;
      }
      esum[j2] = e;
    }
#pragma unroll
    for (int j2 = 0; j2 < 4; ++j2) {
      float e = esum[j2];
      e += __shfl_xor(e, 1, 64);
      e += __shfl_xor(e, 2, 64);
      e += __shfl_xor(e, 4, 64);
      e += __shfl_xor(e, 8, 64);
      if (l15 == 0) atomicAdd(rs + browbase + j2, e);
    }
  }
}

// ---------------------------------------------------------------------------
// Kernel 3: loss = mean(log(rowsum) - tgtlog) per modality
// ---------------------------------------------------------------------------
__global__ void loss_kernel(const float* __restrict__ rowsum,
                            const float* __restrict__ tgtlog,
                            float* __restrict__ out) {
  int t = threadIdx.x;  // 512
  float lr = logf(rowsum[t]) - tgtlog[t];
  float li = logf(rowsum[BATCH + t]) - tgtlog[BATCH + t];
#pragma unroll
  for (int m = 1; m < 64; m <<= 1) { lr += __shfl_xor(lr, m, 64); li += __shfl_xor(li, m, 64); }
  __shared__ float sr[8], si[8];
  if ((t & 63) == 0) { sr[t >> 6] = lr; si[t >> 6] = li; }
  __syncthreads();
  if (t == 0) {
    float a = 0.f, b = 0.f;
#pragma unroll
    for (int i = 0; i < 8; ++i) { a += sr[i]; b += si[i]; }
    out[0] = a * (1.0f / BATCH);
    out[1] = b * (1.0f / BATCH);
  }
}

// ---------------------------------------------------------------------------
// Kernel 4: sequential momentum update chains on the copied banks.
// ---------------------------------------------------------------------------
__global__ void mom_kernel(const int* __restrict__ t_rgb,
                           const int* __restrict__ t_ir,
                           const float* __restrict__ xf,   // [2][512][1024]
                           float* __restrict__ out) {      // out + 2 base
  const int i   = blockIdx.x;
  const int mod = blockIdx.y;
  const int* tg = mod ? t_ir : t_rgb;
  const int y = tg[i];
  for (int j = 0; j < i; ++j)
    if (tg[j] == y) return;          // uniform: another block owns this chain

  const float* x = xf + (size_t)mod * BATCH * DIM;
  float* rowp = out + (size_t)mod * NCLUS * DIM + (size_t)y * DIM;

  const int t = threadIdx.x;  // 256
  float2 r0 = ((const float2*)rowp)[t];
  float2 r1 = ((const float2*)rowp)[t + 256];
  __shared__ float red[4];

  for (int j = i; j < BATCH; ++j) {
    if (tg[j] != y) continue;        // uniform
    const float2* xr = (const float2*)(x + (size_t)j * DIM);
    float2 x0 = xr[t], x1 = xr[t + 256];
    r0.x = 0.9f * r0.x + 0.1f * x0.x;
    r0.y = 0.9f * r0.y + 0.1f * x0.y;
    r1.x = 0.9f * r1.x + 0.1f * x1.x;
    r1.y = 0.9f * r1.y + 0.1f * x1.y;
    float ss = r0.x*r0.x + r0.y*r0.y + r1.x*r1.x + r1.y*r1.y;
#pragma unroll
    for (int m = 1; m < 64; m <<= 1) ss += __shfl_xor(ss, m, 64);
    if ((t & 63) == 0) red[t >> 6] = ss;
    __syncthreads();
    float tot = red[0] + red[1] + red[2] + red[3];
    __syncthreads();
    float inv = 1.0f / sqrtf(tot);
    r0.x *= inv; r0.y *= inv; r1.x *= inv; r1.y *= inv;
  }
  ((float2*)rowp)[t] = r0;
  ((float2*)rowp)[t + 256] = r1;
}

// ---------------------------------------------------------------------------
extern "C" void kernel_launch(void* const* d_in, const int* in_sizes, int n_in,
                              void* d_out, int out_size, void* d_ws, size_t ws_size,
                              hipStream_t stream) {
  (void)in_sizes; (void)n_in; (void)out_size; (void)ws_size;
  const float* in_rgb = (const float*)d_in[0];
  const float* in_ir  = (const float*)d_in[1];
  const int*   t_rgb  = (const int*)d_in[2];
  const int*   t_ir   = (const int*)d_in[3];
  const float* f_rgb  = (const float*)d_in[4];
  const float* f_ir   = (const float*)d_in[5];
  float* out = (float*)d_out;

  char* ws = (char*)d_ws;
  float*          xf     = (float*)ws;                       // 4 MB  [2][512][1024] f32
  unsigned short* xb     = (unsigned short*)(ws + (4u<<20)); // 2 MB  [2][512][1024] bf16
  float*          rowsum = (float*)(ws + (6u<<20));          // 2048 f32 (rowsum+tgtlog)
  float*          tgtlog = rowsum + 1024;

  nrm_kernel<<<1024, 256, 0, stream>>>(in_rgb, in_ir, xf, xb, rowsum);
  fused_kernel<<<2048, 256, 0, stream>>>(xb, f_rgb, f_ir, t_rgb, t_ir,
                                         out + 2, rowsum, tgtlog);
  mom_kernel<<<dim3(512, 2), 256, 0, stream>>>(t_rgb, t_ir, xf, out + 2);
  loss_kernel<<<1, 512, 0, stream>>>(rowsum, tgtlog, out);
}

// Round 11
// 192.403 us; speedup vs baseline: 1.7442x; 1.7442x over previous
//
#include <hip/hip_runtime.h>
#include <math.h>

#define BATCH 512
#define DIM   1024
#define NCLUS 16384
#define TINV  20.0f   // 1/TEMP

typedef __attribute__((ext_vector_type(4))) float f32x4;
typedef __attribute__((ext_vector_type(2))) float f32x2;
typedef __attribute__((ext_vector_type(8))) short bf16x8;

static __device__ __forceinline__ unsigned short f2bf(float f) {
  unsigned int u = __float_as_uint(f);
  u += 0x7FFFu + ((u >> 16) & 1u);   // round-to-nearest-even
  return (unsigned short)(u >> 16);
}

typedef const __attribute__((address_space(1))) unsigned int* gas1_t;
typedef __attribute__((address_space(3))) unsigned int* las3_t;
// async global->LDS, 16B per lane; LDS dest = wave-uniform base + lane*16
static __device__ __forceinline__ void gload16(const void* g, void* l) {
  __builtin_amdgcn_global_load_lds((gas1_t)g, (las3_t)l, 16, 0, 0);
}

// ---------------------------------------------------------------------------
// Kernel 1: row L2-normalize (both modalities), emit f32 + bf16 copies of x.
// Also zeroes the 2048-float accumulator region (rowsum + tgtlog).
// ---------------------------------------------------------------------------
__global__ void nrm_kernel(const float* __restrict__ in_rgb,
                           const float* __restrict__ in_ir,
                           float* __restrict__ xf,            // [2][512][1024]
                           unsigned short* __restrict__ xb,   // [2][512][1024]
                           float* __restrict__ accum) {       // 2048 floats
  int gid = blockIdx.x * blockDim.x + threadIdx.x;
  if (gid < 2048) accum[gid] = 0.0f;

  int row = blockIdx.x;
  int mod = row >> 9;
  int r   = row & 511;
  const float* in = (mod ? in_ir : in_rgb) + (size_t)r * DIM;
  float* xo          = xf + ((size_t)mod * BATCH + r) * DIM;
  unsigned short* xbo = xb + ((size_t)mod * BATCH + r) * DIM;

  int t = threadIdx.x;
  float4 v = ((const float4*)in)[t];
  float ss = v.x*v.x + v.y*v.y + v.z*v.z + v.w*v.w;
#pragma unroll
  for (int m = 1; m < 64; m <<= 1) ss += __shfl_xor(ss, m, 64);
  __shared__ float red[4];
  if ((t & 63) == 0) red[t >> 6] = ss;
  __syncthreads();
  float inv = 1.0f / fmaxf(sqrtf(red[0] + red[1] + red[2] + red[3]), 1e-12f);
  float4 o = make_float4(v.x * inv, v.y * inv, v.z * inv, v.w * inv);
  ((float4*)xo)[t] = o;
  ushort4 ob = make_ushort4(f2bf(o.x), f2bf(o.y), f2bf(o.z), f2bf(o.w));
  ((ushort4*)xbo)[t] = ob;
}

// ---------------------------------------------------------------------------
// Kernel 2: bank copy to d_out (f32 exact, nontemporal) + bf16 convert of F.
// out is only 8B-aligned (d_out+2 floats) -> f32x2 stores there.
// ---------------------------------------------------------------------------
__global__ void cvtcopy_kernel(const float* __restrict__ f_rgb,
                               const float* __restrict__ f_ir,
                               float* __restrict__ out,           // out + 2
                               unsigned short* __restrict__ fb) { // [2][16384][1024] bf16
  const size_t n4 = (size_t)NCLUS * DIM / 4;   // f32x4 per bank
  size_t stride = (size_t)gridDim.x * blockDim.x;
  for (size_t i = (size_t)blockIdx.x * blockDim.x + threadIdx.x; i < 2 * n4; i += stride) {
    const f32x4* src = (i < n4) ? ((const f32x4*)f_rgb) + i
                                : ((const f32x4*)f_ir) + (i - n4);
    const f32x4 v = __builtin_nontemporal_load(src);
    f32x2* o2 = (f32x2*)(out + 4 * i);
    __builtin_nontemporal_store((f32x2){v.x, v.y}, o2);
    __builtin_nontemporal_store((f32x2){v.z, v.w}, o2 + 1);
    ((ushort4*)fb)[i] = make_ushort4(f2bf(v.x), f2bf(v.y), f2bf(v.z), f2bf(v.w));
  }
}

// ---------------------------------------------------------------------------
// Kernel 3: 256x256 bf16 MFMA GEMM + fused exp-sum / target capture.
// m230-quadrant structure: 2-buf LDS (64 KB -> LDS fits 2 blocks/CU),
// plain __syncthreads 2-phase loop (proven at 128² = 86 µs, round 4),
// STAGE(next) issued BEFORE compute of current. 512 threads = 8 waves
// (2 M x 4 N), per-wave output 128x64, acc[8][4]; 32 MFMA + 12 ds_read
// + 4 gload16 per barrier interval (2x the MFMA/barrier of 128²).
// Conflict-free LDS pair verified in rounds 8-9 (SQ_LDS_BANK_CONFLICT=0,
// refcheck'd): source chunk cs=(q&3)^((q>>3)&3), read byte ^ (l15&6)<<3.
// grid (64 nt, 4 = mod*2+bt): linear idx % 8 == nt % 8 -> panel-sharing
// blocks (same nt) land on one XCD.
// ---------------------------------------------------------------------------
#define BM 256
#define BN 256
#define BK 32
#define KT_N (DIM / BK)   // 32 K-tiles

__launch_bounds__(512, 2)
__global__ void gemm_lse_kernel(const unsigned short* __restrict__ xb,
                                const unsigned short* __restrict__ fb,
                                const int* __restrict__ t_rgb,
                                const int* __restrict__ t_ir,
                                float* __restrict__ rowsum,   // [2][512]
                                float* __restrict__ tgtlog) { // [2][512]
  const int nt  = blockIdx.x;        // 0..63
  const int bt  = blockIdx.y & 1;    // batch tile
  const int mod = blockIdx.y >> 1;   // modality

  const unsigned short* X = xb + ((size_t)mod * BATCH + bt * BM) * DIM;
  const unsigned short* F = fb + ((size_t)mod * NCLUS + (size_t)nt * BN) * DIM;
  const int* tg = mod ? t_ir : t_rgb;
  float* rs = rowsum + mod * BATCH;
  float* tl = tgtlog + mod * BATCH;

  __shared__ __align__(16) unsigned short Ab[2][BM * BK];  // 32 KB
  __shared__ __align__(16) unsigned short Bb[2][BN * BK];  // 32 KB

  const int tid  = threadIdx.x;        // 0..511
  const int wid  = tid >> 6;           // 0..7
  const int lane = tid & 63;
  const int wr = wid >> 2, wc = wid & 3;
  const int l15 = lane & 15, lhi = lane >> 4;
  const int sw = (l15 & 6) << 3;       // read-side bank-spread XOR (bytes)

  f32x4 acc[8][4];
#pragma unroll
  for (int m = 0; m < 8; ++m)
#pragma unroll
    for (int n = 0; n < 4; ++n) acc[m][n] = (f32x4){0.f, 0.f, 0.f, 0.f};

  // stage one 16 KB tile (A or B) of K-tile kt into buf: 2 gload16/thread.
  // source chunk inverse-swizzled: cs = (q&3) ^ ((q>>3)&3) (involution, row
  // q>>2 unchanged) so the XOR'd read below retrieves the right bytes.
  auto STAGE_A = [&](int buf, int kt) {
#pragma unroll
    for (int c = 0; c < 2; ++c) {
      int q = c * 512 + tid;                       // chunk 0..1023
      int cs = (q & 3) ^ ((q >> 3) & 3);
      gload16(X + (size_t)(q >> 2) * DIM + kt * BK + cs * 8,
              &Ab[buf][(c * 512 + wid * 64) * 8]);
    }
  };
  auto STAGE_B = [&](int buf, int kt) {
#pragma unroll
    for (int c = 0; c < 2; ++c) {
      int q = c * 512 + tid;
      int cs = (q & 3) ^ ((q >> 3) & 3);
      gload16(F + (size_t)(q >> 2) * DIM + kt * BK + cs * 8,
              &Bb[buf][(c * 512 + wid * 64) * 8]);
    }
  };
  auto LDA = [&](int buf, int row) {
    return *(const bf16x8*)((const char*)Ab[buf] + ((row * (BK * 2) + lhi * 16) ^ sw));
  };
  auto LDB = [&](int buf, int row) {
    return *(const bf16x8*)((const char*)Bb[buf] + ((row * (BK * 2) + lhi * 16) ^ sw));
  };

  // prologue: stage tile 0, full drain once
  STAGE_A(0, 0); STAGE_B(0, 0);
  __syncthreads();

  for (int s = 0; s < KT_N; ++s) {
    const int cur = s & 1;
    if (s + 1 < KT_N) {                 // issue next tile's DMA first
      STAGE_A(cur ^ 1, s + 1);
      STAGE_B(cur ^ 1, s + 1);
    }
    bf16x8 a[8], b[4];
#pragma unroll
    for (int n = 0; n < 4; ++n) b[n] = LDB(cur, wc * 64 + n * 16 + l15);
#pragma unroll
    for (int m = 0; m < 8; ++m) a[m] = LDA(cur, wr * 128 + m * 16 + l15);
#pragma unroll
    for (int m = 0; m < 8; ++m)
#pragma unroll
      for (int n = 0; n < 4; ++n)
        acc[m][n] = __builtin_amdgcn_mfma_f32_16x16x32_bf16(a[m], b[n], acc[m][n], 0, 0, 0);
    __syncthreads();                    // drains vmcnt+lgkm: next tile ready
  }

  // epilogue: exp-sum over this tile's 256 cols + target capture
  // (verified rounds 8-9: brow = bt*BM + wr*128 + (M>>2)*64 + (M&3)*16 + lhi*4)
#pragma unroll
  for (int M = 0; M < 8; ++M) {
    const int browbase = bt * BM + wr * 128 + ((M >> 2) << 6) + ((M & 3) << 4) + (lhi << 2);
    float esum[4];
#pragma unroll
    for (int j = 0; j < 4; ++j) {
      const int brow = browbase + j;
      const int t = tg[brow];
      float e = 0.f;
#pragma unroll
      for (int n = 0; n < 4; ++n) {
        float logit = acc[M][n][j] * TINV;
        e += __expf(logit);
        int col = nt * BN + wc * 64 + n * 16 + l15;
        if (col == t) tl[brow] = logit;
      }
      esum[j] = e;
    }
#pragma unroll
    for (int j = 0; j < 4; ++j) {
      float e = esum[j];
      e += __shfl_xor(e, 1, 64);
      e += __shfl_xor(e, 2, 64);
      e += __shfl_xor(e, 4, 64);
      e += __shfl_xor(e, 8, 64);
      if (l15 == 0) atomicAdd(rs + browbase + j, e);
    }
  }
}

// ---------------------------------------------------------------------------
// Kernel 4: loss = mean(log(rowsum) - tgtlog) per modality
// ---------------------------------------------------------------------------
__global__ void loss_kernel(const float* __restrict__ rowsum,
                            const float* __restrict__ tgtlog,
                            float* __restrict__ out) {
  int t = threadIdx.x;  // 512
  float lr = logf(rowsum[t]) - tgtlog[t];
  float li = logf(rowsum[BATCH + t]) - tgtlog[BATCH + t];
#pragma unroll
  for (int m = 1; m < 64; m <<= 1) { lr += __shfl_xor(lr, m, 64); li += __shfl_xor(li, m, 64); }
  __shared__ float sr[8], si[8];
  if ((t & 63) == 0) { sr[t >> 6] = lr; si[t >> 6] = li; }
  __syncthreads();
  if (t == 0) {
    float a = 0.f, b = 0.f;
#pragma unroll
    for (int i = 0; i < 8; ++i) { a += sr[i]; b += si[i]; }
    out[0] = a * (1.0f / BATCH);
    out[1] = b * (1.0f / BATCH);
  }
}

// ---------------------------------------------------------------------------
// Kernel 5: sequential momentum update chains on the copied banks.
// ---------------------------------------------------------------------------
__global__ void mom_kernel(const int* __restrict__ t_rgb,
                           const int* __restrict__ t_ir,
                           const float* __restrict__ xf,   // [2][512][1024]
                           float* __restrict__ out) {      // out + 2 base
  const int i   = blockIdx.x;
  const int mod = blockIdx.y;
  const int* tg = mod ? t_ir : t_rgb;
  const int y = tg[i];
  for (int j = 0; j < i; ++j)
    if (tg[j] == y) return;          // uniform: another block owns this chain

  const float* x = xf + (size_t)mod * BATCH * DIM;
  float* rowp = out + (size_t)mod * NCLUS * DIM + (size_t)y * DIM;

  const int t = threadIdx.x;  // 256
  float2 r0 = ((const float2*)rowp)[t];
  float2 r1 = ((const float2*)rowp)[t + 256];
  __shared__ float red[4];

  for (int j = i; j < BATCH; ++j) {
    if (tg[j] != y) continue;        // uniform
    const float2* xr = (const float2*)(x + (size_t)j * DIM);
    float2 x0 = xr[t], x1 = xr[t + 256];
    r0.x = 0.9f * r0.x + 0.1f * x0.x;
    r0.y = 0.9f * r0.y + 0.1f * x0.y;
    r1.x = 0.9f * r1.x + 0.1f * x1.x;
    r1.y = 0.9f * r1.y + 0.1f * x1.y;
    float ss = r0.x*r0.x + r0.y*r0.y + r1.x*r1.x + r1.y*r1.y;
#pragma unroll
    for (int m = 1; m < 64; m <<= 1) ss += __shfl_xor(ss, m, 64);
    if ((t & 63) == 0) red[t >> 6] = ss;
    __syncthreads();
    float tot = red[0] + red[1] + red[2] + red[3];
    __syncthreads();
    float inv = 1.0f / sqrtf(tot);
    r0.x *= inv; r0.y *= inv; r1.x *= inv; r1.y *= inv;
  }
  ((float2*)rowp)[t] = r0;
  ((float2*)rowp)[t + 256] = r1;
}

// ---------------------------------------------------------------------------
extern "C" void kernel_launch(void* const* d_in, const int* in_sizes, int n_in,
                              void* d_out, int out_size, void* d_ws, size_t ws_size,
                              hipStream_t stream) {
  (void)in_sizes; (void)n_in; (void)out_size; (void)ws_size;
  const float* in_rgb = (const float*)d_in[0];
  const float* in_ir  = (const float*)d_in[1];
  const int*   t_rgb  = (const int*)d_in[2];
  const int*   t_ir   = (const int*)d_in[3];
  const float* f_rgb  = (const float*)d_in[4];
  const float* f_ir   = (const float*)d_in[5];
  float* out = (float*)d_out;

  char* ws = (char*)d_ws;
  float*          xf     = (float*)ws;                       // 4 MB  [2][512][1024] f32
  unsigned short* xb     = (unsigned short*)(ws + (4u<<20)); // 2 MB  [2][512][1024] bf16
  float*          rowsum = (float*)(ws + (6u<<20));          // 2048 f32 (rowsum+tgtlog)
  float*          tgtlog = rowsum + 1024;
  unsigned short* fb     = (unsigned short*)(ws + (8u<<20)); // 64 MB [2][16384][1024] bf16

  nrm_kernel<<<1024, 256, 0, stream>>>(in_rgb, in_ir, xf, xb, rowsum);
  cvtcopy_kernel<<<8192, 256, 0, stream>>>(f_rgb, f_ir, out + 2, fb);
  gemm_lse_kernel<<<dim3(64, 4), 512, 0, stream>>>(xb, fb, t_rgb, t_ir, rowsum, tgtlog);
  mom_kernel<<<dim3(512, 2), 256, 0, stream>>>(t_rgb, t_ir, xf, out + 2);
  loss_kernel<<<1, 512, 0, stream>>>(rowsum, tgtlog, out);
}

// Round 12
// 167.311 us; speedup vs baseline: 2.0057x; 1.1500x over previous
//
#include <hip/hip_runtime.h>
#include <math.h>

#define BATCH 512
#define DIM   1024
#define NCLUS 16384
#define TINV  20.0f   // 1/TEMP

typedef __attribute__((ext_vector_type(4))) float f32x4;
typedef __attribute__((ext_vector_type(2))) float f32x2;
typedef __attribute__((ext_vector_type(8))) short bf16x8;

static __device__ __forceinline__ unsigned short f2bf(float f) {
  unsigned int u = __float_as_uint(f);
  u += 0x7FFFu + ((u >> 16) & 1u);   // round-to-nearest-even
  return (unsigned short)(u >> 16);
}

typedef const __attribute__((address_space(1))) unsigned int* gas1_t;
typedef __attribute__((address_space(3))) unsigned int* las3_t;
// async global->LDS, 16B per lane; LDS dest = wave-uniform base + lane*16
static __device__ __forceinline__ void gload16(const void* g, void* l) {
  __builtin_amdgcn_global_load_lds((gas1_t)g, (las3_t)l, 16, 0, 0);
}

// ---------------------------------------------------------------------------
// Kernel 1: row L2-normalize (both modalities), emit f32 + bf16 copies of x.
// Also zeroes the 2048-float accumulator region (rowsum + tgtlog).
// ---------------------------------------------------------------------------
__global__ void nrm_kernel(const float* __restrict__ in_rgb,
                           const float* __restrict__ in_ir,
                           float* __restrict__ xf,            // [2][512][1024]
                           unsigned short* __restrict__ xb,   // [2][512][1024]
                           float* __restrict__ accum) {       // 2048 floats
  int gid = blockIdx.x * blockDim.x + threadIdx.x;
  if (gid < 2048) accum[gid] = 0.0f;

  int row = blockIdx.x;
  int mod = row >> 9;
  int r   = row & 511;
  const float* in = (mod ? in_ir : in_rgb) + (size_t)r * DIM;
  float* xo          = xf + ((size_t)mod * BATCH + r) * DIM;
  unsigned short* xbo = xb + ((size_t)mod * BATCH + r) * DIM;

  int t = threadIdx.x;
  float4 v = ((const float4*)in)[t];
  float ss = v.x*v.x + v.y*v.y + v.z*v.z + v.w*v.w;
#pragma unroll
  for (int m = 1; m < 64; m <<= 1) ss += __shfl_xor(ss, m, 64);
  __shared__ float red[4];
  if ((t & 63) == 0) red[t >> 6] = ss;
  __syncthreads();
  float inv = 1.0f / fmaxf(sqrtf(red[0] + red[1] + red[2] + red[3]), 1e-12f);
  float4 o = make_float4(v.x * inv, v.y * inv, v.z * inv, v.w * inv);
  ((float4*)xo)[t] = o;
  ushort4 ob = make_ushort4(f2bf(o.x), f2bf(o.y), f2bf(o.z), f2bf(o.w));
  ((ushort4*)xbo)[t] = ob;
}

// ---------------------------------------------------------------------------
// Kernel 2: FUSED 128x128 bf16 MFMA GEMM + in-loop bank copy + exp-sum/target.
// R4's proven 2-buf structure (86 us) with three changes:
//  (1) B comes straight from f32 F: 4x f32x4 global->reg, truncate-pack to
//      bf16, ds_write directly into the VERIFIED swizzled layout (chunk
//      pos = j ^ ((row>>1)&3); read byte ^ (l15&6)<<3; conflicts=0 in R8-R11).
//      fb buffer + cvtcopy kernel are deleted.
//  (2) each block copies its quarter F-panel (rows it pulls into L2 anyway)
//      to d_out, ONE f32x4 chunk per K-iteration, with a COUNTED gate:
//      issue order copy_load, B_load, A_stage [sched_barrier] ... stores;
//      gate = s_waitcnt vmcnt(2): retires A-stage (needed for next compute),
//      keeps the 2 copy-stores in flight across the barrier (the R6 failure
//      mode, fixed). Store data dep is satisfied by B-pack's implicit wait.
//  (3) __launch_bounds__(256,4) caps VGPR at 128 -> 4 blocks/CU (32KB LDS).
// grid (128 nt, 8 = mod*4+bt): linear idx % 8 == nt % 8 -> the 8 blocks of
// panel nt (all bt, both mod) share one XCD; B-path and copy-path both hit
// that panel in L2.
// ---------------------------------------------------------------------------
#define BM 128
#define BN 128
#define BK 32
#define KT_N (DIM / BK)   // 32

__launch_bounds__(256, 4)
__global__ void gemm_lse_kernel(const unsigned short* __restrict__ xb,
                                const float* __restrict__ f_rgb,
                                const float* __restrict__ f_ir,
                                const int* __restrict__ t_rgb,
                                const int* __restrict__ t_ir,
                                float* __restrict__ outc,     // d_out + 2
                                float* __restrict__ rowsum,   // [2][512]
                                float* __restrict__ tgtlog) { // [2][512]
  const int nt  = blockIdx.x;        // 0..127
  const int bt  = blockIdx.y & 3;    // batch tile
  const int mod = blockIdx.y >> 2;   // modality

  const unsigned short* X = xb + ((size_t)mod * BATCH + bt * BM) * DIM;
  const float* Ff = (mod ? f_ir : f_rgb) + (size_t)nt * BN * DIM;   // panel
  const float* Fq = Ff + (size_t)bt * 32 * DIM;                     // quarter
  float* Oq = outc + ((size_t)mod * NCLUS + (size_t)nt * BN + bt * 32) * DIM;
  const int* tg = mod ? t_ir : t_rgb;
  float* rs = rowsum + mod * BATCH;
  float* tl = tgtlog + mod * BATCH;

  __shared__ __align__(16) unsigned short As[2][BM * BK];  // 16 KB
  __shared__ __align__(16) unsigned short Bs[2][BN * BK];  // 16 KB

  const int tid  = threadIdx.x;
  const int wid  = tid >> 6;
  const int lane = tid & 63;
  const int wr = wid >> 1, wc = wid & 1;
  const int l15 = lane & 15, lhi = lane >> 4;
  const int sw = (l15 & 6) << 3;       // read-side bank-spread XOR (bytes)

  f32x4 acc[4][4];
#pragma unroll
  for (int m = 0; m < 4; ++m)
#pragma unroll
    for (int n = 0; n < 4; ++n) acc[m][n] = (f32x4){0.f, 0.f, 0.f, 0.f};

  // A: verified swizzle pair — source chunk cs=(q&3)^((q>>3)&3) into linear
  // dest, read with byte^sw below (R8-R11: SQ_LDS_BANK_CONFLICT = 0).
  auto A_STAGE = [&](int buf, int kt) {
#pragma unroll
    for (int c = 0; c < 2; ++c) {
      int q = c * 256 + tid;                    // 16B chunk 0..511
      int cs = (q & 3) ^ ((q >> 3) & 3);
      gload16(X + (size_t)(q >> 2) * DIM + kt * BK + cs * 8,
              &As[buf][(c * 256 + wid * 64) * 8]);
    }
  };
  // B: f32 panel rows -> regs (issue early)
  auto B_LOAD = [&](f32x4* br, int kk) {
#pragma unroll
    for (int c = 0; c < 2; ++c) {
      int h = c * 256 + tid, row = h >> 2, j = h & 3;   // bf16 16B-chunk (row,j)
      const float* sp = Ff + (size_t)row * DIM + kk + j * 8;
      br[c * 2]     = *(const f32x4*)sp;
      br[c * 2 + 1] = *(const f32x4*)(sp + 4);
    }
  };
  // pack (truncation; >100x inside error budget) + ds_write at swizzled pos
  auto B_WRITE = [&](int buf, const f32x4* br) {
#pragma unroll
    for (int c = 0; c < 2; ++c) {
      int h = c * 256 + tid, row = h >> 2, j = h & 3;
      union { bf16x8 v; unsigned int w[4]; } p;
      const unsigned int* x0 = (const unsigned int*)&br[c * 2];
      const unsigned int* x1 = (const unsigned int*)&br[c * 2 + 1];
      p.w[0] = (x0[0] >> 16) | (x0[1] & 0xFFFF0000u);
      p.w[1] = (x0[2] >> 16) | (x0[3] & 0xFFFF0000u);
      p.w[2] = (x1[0] >> 16) | (x1[1] & 0xFFFF0000u);
      p.w[3] = (x1[2] >> 16) | (x1[3] & 0xFFFF0000u);
      *(bf16x8*)((char*)&Bs[buf][0] + row * 64 + ((j ^ ((row >> 1) & 3)) << 4)) = p.v;
    }
  };
  auto LDA = [&](int buf, int row) {
    return *(const bf16x8*)((const char*)As[buf] + ((row * 64 + lhi * 16) ^ sw));
  };
  auto LDB = [&](int buf, int row) {
    return *(const bf16x8*)((const char*)Bs[buf] + ((row * 64 + lhi * 16) ^ sw));
  };
  auto COMPUTE = [&](int buf) {
    bf16x8 a[4], b[4];
#pragma unroll
    for (int n = 0; n < 4; ++n) b[n] = LDB(buf, wc * 64 + n * 16 + l15);
#pragma unroll
    for (int m = 0; m < 4; ++m) a[m] = LDA(buf, wr * 64 + m * 16 + l15);
#pragma unroll
    for (int m = 0; m < 4; ++m)
#pragma unroll
      for (int n = 0; n < 4; ++n)
        acc[m][n] = __builtin_amdgcn_mfma_f32_16x16x32_bf16(a[m], b[n], acc[m][n], 0, 0, 0);
  };

  // prologue: K-tile 0, full drain once
  {
    f32x4 br0[4];
    B_LOAD(br0, 0);
    A_STAGE(0, 0);
    B_WRITE(0, br0);
  }
  __syncthreads();

  for (int s = 0; s < KT_N; ++s) {
    const int cur = s & 1;
    // ---- issue phase (pinned before marker) ----
    const int id = s * 256 + tid;                 // copy chunk: 32 rows x 256
    const int r32 = id >> 8, col = id & 255;
    f32x4 craw = *((const f32x4*)(Fq + (size_t)r32 * DIM) + col);
    f32x4 braw[4];
    if (s + 1 < KT_N) {
      B_LOAD(braw, (s + 1) * BK);
      A_STAGE(cur ^ 1, s + 1);
    }
    __builtin_amdgcn_sched_barrier(0);
    // ---- compute on resident buffers (loads in flight above) ----
    COMPUTE(cur);
    if (s + 1 < KT_N) B_WRITE(cur ^ 1, braw);     // implicit wait retires B+copy loads
    // ---- copy store (data ready; stores are newest VMEM) ----
    {
      float* dp = Oq + (size_t)r32 * DIM + (size_t)col * 4;
      __builtin_nontemporal_store((f32x2){craw.x, craw.y}, (f32x2*)dp);
      __builtin_nontemporal_store((f32x2){craw.z, craw.w}, (f32x2*)(dp + 2));
    }
    if (s + 1 < KT_N) {
      // counted gate: retire A-stage (2), keep the 2 copy-stores in flight
      asm volatile("s_waitcnt vmcnt(2) lgkmcnt(0)" ::: "memory");
      __builtin_amdgcn_sched_barrier(0);
      __builtin_amdgcn_s_barrier();
    }
  }

  // epilogue: exp-sum over this tile's 128 cols + target capture (R4-verified)
#pragma unroll
  for (int m = 0; m < 4; ++m) {
    const int browbase = bt * BM + wr * 64 + m * 16 + lhi * 4;
    float esum[4];
#pragma unroll
    for (int j = 0; j < 4; ++j) {
      const int brow = browbase + j;
      const int t = tg[brow];
      float e = 0.f;
#pragma unroll
      for (int n = 0; n < 4; ++n) {
        float logit = acc[m][n][j] * TINV;
        e += __expf(logit);
        int col = nt * BN + wc * 64 + n * 16 + l15;
        if (col == t) tl[brow] = logit;
      }
      esum[j] = e;
    }
#pragma unroll
    for (int j = 0; j < 4; ++j) {
      float e = esum[j];
      e += __shfl_xor(e, 1, 64);
      e += __shfl_xor(e, 2, 64);
      e += __shfl_xor(e, 4, 64);
      e += __shfl_xor(e, 8, 64);
      if (l15 == 0) atomicAdd(rs + browbase + j, e);
    }
  }
}

// ---------------------------------------------------------------------------
// Kernel 3: loss = mean(log(rowsum) - tgtlog) per modality
// ---------------------------------------------------------------------------
__global__ void loss_kernel(const float* __restrict__ rowsum,
                            const float* __restrict__ tgtlog,
                            float* __restrict__ out) {
  int t = threadIdx.x;  // 512
  float lr = logf(rowsum[t]) - tgtlog[t];
  float li = logf(rowsum[BATCH + t]) - tgtlog[BATCH + t];
#pragma unroll
  for (int m = 1; m < 64; m <<= 1) { lr += __shfl_xor(lr, m, 64); li += __shfl_xor(li, m, 64); }
  __shared__ float sr[8], si[8];
  if ((t & 63) == 0) { sr[t >> 6] = lr; si[t >> 6] = li; }
  __syncthreads();
  if (t == 0) {
    float a = 0.f, b = 0.f;
#pragma unroll
    for (int i = 0; i < 8; ++i) { a += sr[i]; b += si[i]; }
    out[0] = a * (1.0f / BATCH);
    out[1] = b * (1.0f / BATCH);
  }
}

// ---------------------------------------------------------------------------
// Kernel 4: sequential momentum update chains on the copied banks.
// ---------------------------------------------------------------------------
__global__ void mom_kernel(const int* __restrict__ t_rgb,
                           const int* __restrict__ t_ir,
                           const float* __restrict__ xf,   // [2][512][1024]
                           float* __restrict__ out) {      // out + 2 base
  const int i   = blockIdx.x;
  const int mod = blockIdx.y;
  const int* tg = mod ? t_ir : t_rgb;
  const int y = tg[i];
  for (int j = 0; j < i; ++j)
    if (tg[j] == y) return;          // uniform: another block owns this chain

  const float* x = xf + (size_t)mod * BATCH * DIM;
  float* rowp = out + (size_t)mod * NCLUS * DIM + (size_t)y * DIM;

  const int t = threadIdx.x;  // 256
  float2 r0 = ((const float2*)rowp)[t];
  float2 r1 = ((const float2*)rowp)[t + 256];
  __shared__ float red[4];

  for (int j = i; j < BATCH; ++j) {
    if (tg[j] != y) continue;        // uniform
    const float2* xr = (const float2*)(x + (size_t)j * DIM);
    float2 x0 = xr[t], x1 = xr[t + 256];
    r0.x = 0.9f * r0.x + 0.1f * x0.x;
    r0.y = 0.9f * r0.y + 0.1f * x0.y;
    r1.x = 0.9f * r1.x + 0.1f * x1.x;
    r1.y = 0.9f * r1.y + 0.1f * x1.y;
    float ss = r0.x*r0.x + r0.y*r0.y + r1.x*r1.x + r1.y*r1.y;
#pragma unroll
    for (int m = 1; m < 64; m <<= 1) ss += __shfl_xor(ss, m, 64);
    if ((t & 63) == 0) red[t >> 6] = ss;
    __syncthreads();
    float tot = red[0] + red[1] + red[2] + red[3];
    __syncthreads();
    float inv = 1.0f / sqrtf(tot);
    r0.x *= inv; r0.y *= inv; r1.x *= inv; r1.y *= inv;
  }
  ((float2*)rowp)[t] = r0;
  ((float2*)rowp)[t + 256] = r1;
}

// ---------------------------------------------------------------------------
extern "C" void kernel_launch(void* const* d_in, const int* in_sizes, int n_in,
                              void* d_out, int out_size, void* d_ws, size_t ws_size,
                              hipStream_t stream) {
  (void)in_sizes; (void)n_in; (void)out_size; (void)ws_size;
  const float* in_rgb = (const float*)d_in[0];
  const float* in_ir  = (const float*)d_in[1];
  const int*   t_rgb  = (const int*)d_in[2];
  const int*   t_ir   = (const int*)d_in[3];
  const float* f_rgb  = (const float*)d_in[4];
  const float* f_ir   = (const float*)d_in[5];
  float* out = (float*)d_out;

  char* ws = (char*)d_ws;
  float*          xf     = (float*)ws;                       // 4 MB  [2][512][1024] f32
  unsigned short* xb     = (unsigned short*)(ws + (4u<<20)); // 2 MB  [2][512][1024] bf16
  float*          rowsum = (float*)(ws + (6u<<20));          // 2048 f32 (rowsum+tgtlog)
  float*          tgtlog = rowsum + 1024;

  nrm_kernel<<<1024, 256, 0, stream>>>(in_rgb, in_ir, xf, xb, rowsum);
  gemm_lse_kernel<<<dim3(128, 8), 256, 0, stream>>>(xb, f_rgb, f_ir, t_rgb, t_ir,
                                                    out + 2, rowsum, tgtlog);
  mom_kernel<<<dim3(512, 2), 256, 0, stream>>>(t_rgb, t_ir, xf, out + 2);
  loss_kernel<<<1, 512, 0, stream>>>(rowsum, tgtlog, out);
}